// Round 5
// baseline (726.460 us; speedup 1.0000x reference)
//
#include <hip/hip_runtime.h>

typedef __bf16  bf16x8 __attribute__((ext_vector_type(8)));
typedef float   f32x4  __attribute__((ext_vector_type(4)));
typedef unsigned int uint32x2 __attribute__((ext_vector_type(2)));

#define MFMA16(a,b,c) __builtin_amdgcn_mfma_f32_16x16x32_bf16((a),(b),(c),0,0,0)

template<int V> struct ic_t { static constexpr int value = V; };

// bf16 weight arena layout in d_ws (elements)
enum : int {
    OFF_W0 = 0,                      // [256][64]
    OFF_W1 = OFF_W0 + 256 * 64,      // [256][256]
    OFF_W2 = OFF_W1 + 256 * 256,
    OFF_W3 = OFF_W2 + 256 * 256,
    OFF_W4 = OFF_W3 + 256 * 256,     // [256][320]
    OFF_W5 = OFF_W4 + 256 * 320,
    OFF_W6 = OFF_W5 + 256 * 256,
    OFF_W7 = OFF_W6 + 256 * 256,
    OFF_WF = OFF_W7 + 256 * 256,     // [256][256]
    OFF_WD = OFF_WF + 256 * 256,     // [128][288]
    W_TOTAL = OFF_WD + 128 * 288
};

__device__ __forceinline__ unsigned short f2bf(float f) {
    unsigned int u = __float_as_uint(f);
    u += 0x7FFFu + ((u >> 16) & 1u);
    return (unsigned short)(u >> 16);
}

__device__ __forceinline__ void prep_one(const float* __restrict__ src,
                                         unsigned short* __restrict__ dst,
                                         int fout, int Kp, int n1, int n2, int n3,
                                         int idx) {
    int n = idx / Kp;
    int k = idx - n * Kp;
    float v = 0.f;
    if (k < n1)                 v = src[k * fout + n];
    else if (k >= n2 && k < n3) v = src[(k - (n2 - n1)) * fout + n];
    dst[n * Kp + k] = f2bf(v);
}

__global__ void prep_kernel(const float* w0, const float* w1, const float* w2,
                            const float* w3, const float* w4, const float* w5,
                            const float* w6, const float* w7, const float* wf,
                            const float* wd, unsigned short* dst) {
    int i = blockIdx.x * 256 + threadIdx.x;
    if (i < 256 * 64)  { prep_one(w0, dst + OFF_W0, 256,  64,  63,  64,  64, i); return; }
    i -= 256 * 64;
    if (i < 256 * 256) { prep_one(w1, dst + OFF_W1, 256, 256, 256, 256, 256, i); return; }
    i -= 256 * 256;
    if (i < 256 * 256) { prep_one(w2, dst + OFF_W2, 256, 256, 256, 256, 256, i); return; }
    i -= 256 * 256;
    if (i < 256 * 256) { prep_one(w3, dst + OFF_W3, 256, 256, 256, 256, 256, i); return; }
    i -= 256 * 256;
    if (i < 256 * 320) { prep_one(w4, dst + OFF_W4, 256, 320,  63,  64, 320, i); return; }
    i -= 256 * 320;
    if (i < 256 * 256) { prep_one(w5, dst + OFF_W5, 256, 256, 256, 256, 256, i); return; }
    i -= 256 * 256;
    if (i < 256 * 256) { prep_one(w6, dst + OFF_W6, 256, 256, 256, 256, 256, i); return; }
    i -= 256 * 256;
    if (i < 256 * 256) { prep_one(w7, dst + OFF_W7, 256, 256, 256, 256, 256, i); return; }
    i -= 256 * 256;
    if (i < 256 * 256) { prep_one(wf, dst + OFF_WF, 256, 256, 256, 256, 256, i); return; }
    i -= 256 * 256;
    if (i < 128 * 288) { prep_one(wd, dst + OFF_WD, 128, 288, 286, 288, 288, i); return; }
}

struct Params {
    const float* x;
    const unsigned short* Wt;
    const float* b[8];
    const float* bfv;
    const float* bdv;
    const float* wsv;
    const float* bsv;
    const float* wrv;
    const float* brv;
    float* out;
};

// 64 rows/block, 8 waves (512 thr), N-split 32 cols/wave. Swapped-operand MFMA
// (D=[neuron][batch]) -> packed b64 epilogue, bias folded into acc init.
// Depth-2 B prefetch crossing layer boundaries. 2 blocks/CU -> 4 waves/SIMD.
__global__ __launch_bounds__(512, 4) void nerf_kernel(Params P) {
    __shared__ char Hs0[32768];   // [64][256] bf16, swz ^((row&7)<<4)
    __shared__ char Hs1[32768];
    __shared__ char Xs[8192];     // [64][64] bf16, swz ^((row&7)<<4)
    __shared__ char Ds[4096];     // [64][32] bf16, swz ^((row&3)<<4) (in-row)

    const int t    = threadIdx.x;
    const int lane = t & 63;
    const int wave = t >> 6;          // 0..7
    const int lr   = lane & 15;
    const int lk   = lane >> 4;
    const int blockRow = blockIdx.x << 6;

    // ---- B pipeline (persistent across layers), NT <= 2
    bf16x8 bp0[2], bp1[2], bp2[2];
    {   // preload layer-0 kt0/kt1 (overlaps staging below)
        const unsigned short* Wb0 = P.Wt + OFF_W0 + (size_t)((wave << 5) + lr) * 64 + (lk << 3);
#pragma unroll
        for (int nt = 0; nt < 2; ++nt) {
            bp0[nt] = *(const bf16x8*)(Wb0 + (size_t)(nt << 4) * 64);
            bp1[nt] = *(const bf16x8*)(Wb0 + (size_t)(nt << 4) * 64 + 32);
        }
    }

    // ---- stage x coalesced into Xs/Ds ----
    {
        const float4* xb = (const float4*)(P.x + (size_t)blockRow * 93);
        for (int i = t; i < 1488; i += 512) {          // 64*93/4
            float4 v = xb[i];
            float vv[4] = {v.x, v.y, v.z, v.w};
#pragma unroll
            for (int j = 0; j < 4; ++j) {
                int e = (i << 2) + j;
                int r = e / 93;
                int c = e - r * 93;
                __bf16 us = (__bf16)vv[j];
                if (c < 63)
                    *(__bf16*)(Xs + ((r * 128 + c * 2) ^ ((r & 7) << 4))) = us;
                else
                    *(__bf16*)(Ds + ((r * 64 + (c - 63) * 2) ^ ((r & 3) << 4))) = us;
            }
        }
        if (t < 64) {  // zero pads: Xs col63, Ds cols 30,31
            int r = t;
            *(__bf16*)(Xs + ((r * 128 + 126) ^ ((r & 7) << 4))) = (__bf16)0.f;
            *(__bf16*)(Ds + ((r * 64 + 60) ^ ((r & 3) << 4))) = (__bf16)0.f;
            *(__bf16*)(Ds + ((r * 64 + 62) ^ ((r & 3) << 4))) = (__bf16)0.f;
        }
    }
    __syncthreads();

    // A-fragment getters (activation rows): row = mt*16+lr, k contiguous 16B
    auto ldH = [&](const char* B, int mt, int kt) -> bf16x8 {
        int row = (mt << 4) + lr;
        int off = (row * 512 + (kt << 6) + (lk << 4)) ^ ((row & 7) << 4);
        return *(const bf16x8*)(B + off);
    };
    auto ldXs = [&](int mt, int kt) -> bf16x8 {
        int row = (mt << 4) + lr;
        int off = (row * 128 + (kt << 6) + (lk << 4)) ^ ((row & 7) << 4);
        return *(const bf16x8*)(Xs + off);
    };
    auto ldDs = [&](int mt) -> bf16x8 {
        int row = (mt << 4) + lr;
        int off = (row * 64 + (lk << 4)) ^ ((row & 3) << 4);
        return *(const bf16x8*)(Ds + off);
    };

    // GEMM layer. KT = K/32, NT = N-tiles/wave, NTn = next layer's NT (0=none).
    auto gemm = [&](auto KTt, auto NTt, auto NTnt, auto&& getA,
                    const unsigned short* W, int Kp, const float* bias, bool dorelu,
                    char* dst, const unsigned short* Wn, int Kpn, int cbn) {
        constexpr int KT  = decltype(KTt)::value;
        constexpr int NT  = decltype(NTt)::value;
        constexpr int NTn = decltype(NTnt)::value;
        const int colbase = wave * (NT << 4);
        const unsigned short* Wb = W + (size_t)(colbase + lr) * Kp + (lk << 3);
        const unsigned short* Wbn = (NTn > 0) ? Wn + (size_t)(cbn + lr) * Kpn + (lk << 3) : nullptr;

        // bias folded into acc init (neuron = colbase + nt*16 + lk*4 + e)
        f32x4 acc[4][NT];
        {
            f32x4 bfr[NT];
#pragma unroll
            for (int nt = 0; nt < NT; ++nt)
                bfr[nt] = *(const f32x4*)(bias + colbase + (nt << 4) + (lk << 2));
#pragma unroll
            for (int mt = 0; mt < 4; ++mt)
#pragma unroll
                for (int nt = 0; nt < NT; ++nt) acc[mt][nt] = bfr[nt];
        }

        bf16x8 aC[4], aN[4];
#pragma unroll
        for (int mt = 0; mt < 4; ++mt) { aC[mt] = getA(mt, 0); aN[mt] = aC[mt]; }

#pragma unroll
        for (int kt = 0; kt < KT; ++kt) {
            // B prefetch for index kt+2 (wraps into next layer's kt0/kt1)
            if (kt + 2 < KT) {
#pragma unroll
                for (int nt = 0; nt < NT; ++nt)
                    bp2[nt] = *(const bf16x8*)(Wb + (size_t)(nt << 4) * Kp + ((kt + 2) << 5));
            } else if (NTn > 0) {
#pragma unroll
                for (int nt = 0; nt < (NTn > 0 ? NTn : 1); ++nt)
                    bp2[nt] = *(const bf16x8*)(Wbn + (size_t)(nt << 4) * Kpn + ((kt + 2 - KT) << 5));
            }
            // A prefetch distance 1
            if (kt + 1 < KT) {
#pragma unroll
                for (int mt = 0; mt < 4; ++mt) aN[mt] = getA(mt, kt + 1);
            }
            __builtin_amdgcn_s_setprio(1);
#pragma unroll
            for (int nt = 0; nt < NT; ++nt) {
#pragma unroll
                for (int mt = 0; mt < 4; ++mt)
                    acc[mt][nt] = MFMA16(bp0[nt], aC[mt], acc[mt][nt]);  // D=[neuron][batch]
            }
            __builtin_amdgcn_s_setprio(0);
#pragma unroll
            for (int nt = 0; nt < 2; ++nt) { bp0[nt] = bp1[nt]; bp1[nt] = bp2[nt]; }
#pragma unroll
            for (int mt = 0; mt < 4; ++mt) aC[mt] = aN[mt];
        }

        // epilogue: relu, pack 2x bf16 via cvt_pk, one b64 LDS write per tile
#pragma unroll
        for (int nt = 0; nt < NT; ++nt) {
#pragma unroll
            for (int mt = 0; mt < 4; ++mt) {
                f32x4 v = acc[mt][nt];
                if (dorelu) {
#pragma unroll
                    for (int e = 0; e < 4; ++e) v[e] = fmaxf(v[e], 0.f);
                }
                unsigned int lo, hi;
                asm("v_cvt_pk_bf16_f32 %0, %1, %2" : "=v"(lo) : "v"(v[0]), "v"(v[1]));
                asm("v_cvt_pk_bf16_f32 %0, %1, %2" : "=v"(hi) : "v"(v[2]), "v"(v[3]));
                int batch = (mt << 4) + lr;
                int off = (batch * 512 + ((colbase + (nt << 4) + (lk << 2)) << 1)) ^ ((batch & 7) << 4);
                uint32x2 w2 = {lo, hi};
                *(uint32x2*)(dst + off) = w2;
            }
        }
    };

    const unsigned short* Wt = P.Wt;
    char* cur = Hs0;
    char* alt = Hs1;

    // L0: K=64 from Xs -> cur; next = W1
    gemm(ic_t<2>{}, ic_t<2>{}, ic_t<2>{},
         [&](int mt, int kt) { return ldXs(mt, kt); },
         Wt + OFF_W0, 64, P.b[0], true, cur, Wt + OFF_W1, 256, wave << 5);
    __syncthreads();

    // L1-3
    {
        const unsigned short* Wc[3] = {Wt + OFF_W1, Wt + OFF_W2, Wt + OFF_W3};
        const unsigned short* Wn[3] = {Wt + OFF_W2, Wt + OFF_W3, Wt + OFF_W4};
        const int Kpn[3] = {256, 256, 320};
        const float* bc[3] = {P.b[1], P.b[2], P.b[3]};
        for (int i = 0; i < 3; ++i) {
            gemm(ic_t<8>{}, ic_t<2>{}, ic_t<2>{},
                 [&](int mt, int kt) { return ldH(cur, mt, kt); },
                 Wc[i], 256, bc[i], true, alt, Wn[i], Kpn[i], wave << 5);
            __syncthreads();
            char* tmp = cur; cur = alt; alt = tmp;
        }
    }

    // L4: K=320 = [xyz(64) | h(256)]; next = W5
    gemm(ic_t<10>{}, ic_t<2>{}, ic_t<2>{},
         [&](int mt, int kt) { return (kt < 2) ? ldXs(mt, kt) : ldH(cur, mt, kt - 2); },
         Wt + OFF_W4, 320, P.b[4], true, alt, Wt + OFF_W5, 256, wave << 5);
    __syncthreads();
    { char* tmp = cur; cur = alt; alt = tmp; }

    // L5-7
    {
        const unsigned short* Wc[3] = {Wt + OFF_W5, Wt + OFF_W6, Wt + OFF_W7};
        const unsigned short* Wn[3] = {Wt + OFF_W6, Wt + OFF_W7, Wt + OFF_WF};
        const float* bc[3] = {P.b[5], P.b[6], P.b[7]};
        for (int i = 0; i < 3; ++i) {
            gemm(ic_t<8>{}, ic_t<2>{}, ic_t<2>{},
                 [&](int mt, int kt) { return ldH(cur, mt, kt); },
                 Wc[i], 256, bc[i], true, alt, Wn[i], 256, wave << 5);
            __syncthreads();
            char* tmp = cur; cur = alt; alt = tmp;
        }
    }
    // cur = h (layer-7 out)

    // sigma = h @ ws + bs (read-only on cur; 8 threads/row over 256 cols)
    float sig;
    {
        int rr = t >> 3, q = t & 7;
        float sp = 0.f;
#pragma unroll
        for (int j = 0; j < 4; ++j) {
            int cb = (q << 5) + (j << 3);
            bf16x8 h8 = *(const bf16x8*)(cur + ((rr * 512 + (cb << 1)) ^ ((rr & 7) << 4)));
#pragma unroll
            for (int e = 0; e < 8; ++e) sp += (float)h8[e] * P.wsv[cb + e];
        }
        sp += __shfl_xor(sp, 1);
        sp += __shfl_xor(sp, 2);
        sp += __shfl_xor(sp, 4);
        sig = sp + P.bsv[0];
    }

    // xyz_final = h @ wf + bf (no relu); next = WD (NT=1, Kp=288, colbase wave*16)
    gemm(ic_t<8>{}, ic_t<2>{}, ic_t<1>{},
         [&](int mt, int kt) { return ldH(cur, mt, kt); },
         Wt + OFF_WF, 256, P.bfv, false, alt, Wt + OFF_WD, 288, wave << 4);
    __syncthreads();
    { char* tmp = cur; cur = alt; alt = tmp; }
    // cur = xyz_final, alt = h (dead)

    // d = relu([xyz_final | dir] @ wd + bd): KT=9, NT=1 -> alt cols 0..127
    gemm(ic_t<9>{}, ic_t<1>{}, ic_t<0>{},
         [&](int mt, int kt) { return (kt < 8) ? ldH(cur, mt, kt) : ldDs(mt); },
         Wt + OFF_WD, 288, P.bdv, true, alt, nullptr, 0, 0);
    __syncthreads();

    // rgb = sigmoid(d @ wr + br); fused float4 store {r,g,b,sigma}
    {
        int rr = t >> 3, q = t & 7;
        float c0 = 0.f, c1 = 0.f, c2 = 0.f;
#pragma unroll
        for (int j = 0; j < 2; ++j) {
            int kb = (q << 4) + (j << 3);
            bf16x8 d8 = *(const bf16x8*)(alt + ((rr * 512 + (kb << 1)) ^ ((rr & 7) << 4)));
#pragma unroll
            for (int e = 0; e < 8; ++e) {
                float dv = (float)d8[e];
                const float* w = P.wrv + (kb + e) * 3;
                c0 += dv * w[0]; c1 += dv * w[1]; c2 += dv * w[2];
            }
        }
        c0 += __shfl_xor(c0, 1); c0 += __shfl_xor(c0, 2); c0 += __shfl_xor(c0, 4);
        c1 += __shfl_xor(c1, 1); c1 += __shfl_xor(c1, 2); c1 += __shfl_xor(c1, 4);
        c2 += __shfl_xor(c2, 1); c2 += __shfl_xor(c2, 2); c2 += __shfl_xor(c2, 4);
        if (q == 0) {
            float4 o;
            o.x = 1.f / (1.f + __expf(-(c0 + P.brv[0])));
            o.y = 1.f / (1.f + __expf(-(c1 + P.brv[1])));
            o.z = 1.f / (1.f + __expf(-(c2 + P.brv[2])));
            o.w = sig;
            ((float4*)P.out)[blockRow + rr] = o;
        }
    }
}

extern "C" void kernel_launch(void* const* d_in, const int* in_sizes, int n_in,
                              void* d_out, int out_size, void* d_ws, size_t ws_size,
                              hipStream_t stream) {
    const float* x = (const float*)d_in[0];
    const float* w[8];
    const float* b[8];
    for (int i = 0; i < 8; ++i) {
        w[i] = (const float*)d_in[1 + 2 * i];
        b[i] = (const float*)d_in[2 + 2 * i];
    }
    const float* wf  = (const float*)d_in[17];
    const float* bfv = (const float*)d_in[18];
    const float* wd  = (const float*)d_in[19];
    const float* bdv = (const float*)d_in[20];
    const float* wsv = (const float*)d_in[21];
    const float* bsv = (const float*)d_in[22];
    const float* wrv = (const float*)d_in[23];
    const float* brv = (const float*)d_in[24];

    unsigned short* Wt = (unsigned short*)d_ws;

    prep_kernel<<<(W_TOTAL + 255) / 256, 256, 0, stream>>>(
        w[0], w[1], w[2], w[3], w[4], w[5], w[6], w[7], wf, wd, Wt);

    Params P;
    P.x = x; P.Wt = Wt;
    for (int i = 0; i < 8; ++i) P.b[i] = b[i];
    P.bfv = bfv; P.bdv = bdv; P.wsv = wsv; P.bsv = bsv; P.wrv = wrv; P.brv = brv;
    P.out = (float*)d_out;

    nerf_kernel<<<262144 / 64, 512, 0, stream>>>(P);
}

// Round 6
// 622.178 us; speedup vs baseline: 1.1676x; 1.1676x over previous
//
#include <hip/hip_runtime.h>

typedef __bf16  bf16x8 __attribute__((ext_vector_type(8)));
typedef float   f32x4  __attribute__((ext_vector_type(4)));
typedef unsigned int uint32x2 __attribute__((ext_vector_type(2)));

#define MFMA16(a,b,c) __builtin_amdgcn_mfma_f32_16x16x32_bf16((a),(b),(c),0,0,0)

template<int V> struct ic_t { static constexpr int value = V; };

// bf16 weight arena layout in d_ws (elements)
enum : int {
    OFF_W0 = 0,                      // [256][64]
    OFF_W1 = OFF_W0 + 256 * 64,      // [256][256]
    OFF_W2 = OFF_W1 + 256 * 256,
    OFF_W3 = OFF_W2 + 256 * 256,
    OFF_W4 = OFF_W3 + 256 * 256,     // [256][320]
    OFF_W5 = OFF_W4 + 256 * 320,
    OFF_W6 = OFF_W5 + 256 * 256,
    OFF_W7 = OFF_W6 + 256 * 256,
    OFF_WF = OFF_W7 + 256 * 256,     // [256][256]
    OFF_WD = OFF_WF + 256 * 256,     // [128][288]
    W_TOTAL = OFF_WD + 128 * 288
};

__device__ __forceinline__ unsigned short f2bf(float f) {
    unsigned int u = __float_as_uint(f);
    u += 0x7FFFu + ((u >> 16) & 1u);
    return (unsigned short)(u >> 16);
}

__device__ __forceinline__ void prep_one(const float* __restrict__ src,
                                         unsigned short* __restrict__ dst,
                                         int fout, int Kp, int n1, int n2, int n3,
                                         int idx) {
    int n = idx / Kp;
    int k = idx - n * Kp;
    float v = 0.f;
    if (k < n1)                 v = src[k * fout + n];
    else if (k >= n2 && k < n3) v = src[(k - (n2 - n1)) * fout + n];
    dst[n * Kp + k] = f2bf(v);
}

__global__ void prep_kernel(const float* w0, const float* w1, const float* w2,
                            const float* w3, const float* w4, const float* w5,
                            const float* w6, const float* w7, const float* wf,
                            const float* wd, unsigned short* dst) {
    int i = blockIdx.x * 256 + threadIdx.x;
    if (i < 256 * 64)  { prep_one(w0, dst + OFF_W0, 256,  64,  63,  64,  64, i); return; }
    i -= 256 * 64;
    if (i < 256 * 256) { prep_one(w1, dst + OFF_W1, 256, 256, 256, 256, 256, i); return; }
    i -= 256 * 256;
    if (i < 256 * 256) { prep_one(w2, dst + OFF_W2, 256, 256, 256, 256, 256, i); return; }
    i -= 256 * 256;
    if (i < 256 * 256) { prep_one(w3, dst + OFF_W3, 256, 256, 256, 256, 256, i); return; }
    i -= 256 * 256;
    if (i < 256 * 320) { prep_one(w4, dst + OFF_W4, 256, 320,  63,  64, 320, i); return; }
    i -= 256 * 320;
    if (i < 256 * 256) { prep_one(w5, dst + OFF_W5, 256, 256, 256, 256, 256, i); return; }
    i -= 256 * 256;
    if (i < 256 * 256) { prep_one(w6, dst + OFF_W6, 256, 256, 256, 256, 256, i); return; }
    i -= 256 * 256;
    if (i < 256 * 256) { prep_one(w7, dst + OFF_W7, 256, 256, 256, 256, 256, i); return; }
    i -= 256 * 256;
    if (i < 256 * 256) { prep_one(wf, dst + OFF_WF, 256, 256, 256, 256, 256, i); return; }
    i -= 256 * 256;
    if (i < 128 * 288) { prep_one(wd, dst + OFF_WD, 128, 288, 286, 288, 288, i); return; }
}

struct Params {
    const float* x;
    const unsigned short* Wt;
    const float* b[8];
    const float* bfv;
    const float* bdv;
    const float* wsv;
    const float* bsv;
    const float* wrv;
    const float* brv;
    float* out;
};

// 64 rows/block, 8 waves (512 thr), N-split 32 cols/wave. Swapped-operand MFMA
// (D=[neuron][batch]) -> packed b64 epilogue, bias folded into acc init.
// Depth-2 B prefetch crossing layer boundaries.
// __launch_bounds__(512,2): 2 blocks/CU (LDS-limited anyway) -> 4 waves/SIMD,
// VGPR cap 128 (R5's (512,4) forced a 64-VGPR cap -> catastrophic spills).
__global__ __launch_bounds__(512, 2) void nerf_kernel(Params P) {
    __shared__ char Hs0[32768];   // [64][256] bf16, swz ^((row&7)<<4)
    __shared__ char Hs1[32768];
    __shared__ char Xs[8192];     // [64][64] bf16, swz ^((row&7)<<4)
    __shared__ char Ds[4096];     // [64][32] bf16, swz ^((row&3)<<4) (in-row)

    const int t    = threadIdx.x;
    const int lane = t & 63;
    const int wave = t >> 6;          // 0..7
    const int lr   = lane & 15;
    const int lk   = lane >> 4;
    const int blockRow = blockIdx.x << 6;

    // ---- B pipeline (persistent across layers), NT <= 2
    bf16x8 bp0[2], bp1[2], bp2[2];
    {   // preload layer-0 kt0/kt1 (overlaps staging below)
        const unsigned short* Wb0 = P.Wt + OFF_W0 + (size_t)((wave << 5) + lr) * 64 + (lk << 3);
#pragma unroll
        for (int nt = 0; nt < 2; ++nt) {
            bp0[nt] = *(const bf16x8*)(Wb0 + (size_t)(nt << 4) * 64);
            bp1[nt] = *(const bf16x8*)(Wb0 + (size_t)(nt << 4) * 64 + 32);
        }
    }

    // ---- stage x coalesced into Xs/Ds ----
    {
        const float4* xb = (const float4*)(P.x + (size_t)blockRow * 93);
        for (int i = t; i < 1488; i += 512) {          // 64*93/4
            float4 v = xb[i];
            float vv[4] = {v.x, v.y, v.z, v.w};
#pragma unroll
            for (int j = 0; j < 4; ++j) {
                int e = (i << 2) + j;
                int r = e / 93;
                int c = e - r * 93;
                __bf16 us = (__bf16)vv[j];
                if (c < 63)
                    *(__bf16*)(Xs + ((r * 128 + c * 2) ^ ((r & 7) << 4))) = us;
                else
                    *(__bf16*)(Ds + ((r * 64 + (c - 63) * 2) ^ ((r & 3) << 4))) = us;
            }
        }
        if (t < 64) {  // zero pads: Xs col63, Ds cols 30,31
            int r = t;
            *(__bf16*)(Xs + ((r * 128 + 126) ^ ((r & 7) << 4))) = (__bf16)0.f;
            *(__bf16*)(Ds + ((r * 64 + 60) ^ ((r & 3) << 4))) = (__bf16)0.f;
            *(__bf16*)(Ds + ((r * 64 + 62) ^ ((r & 3) << 4))) = (__bf16)0.f;
        }
    }
    __syncthreads();

    // A-fragment getters (activation rows): row = mt*16+lr, k contiguous 16B
    auto ldH = [&](const char* B, int mt, int kt) -> bf16x8 {
        int row = (mt << 4) + lr;
        int off = (row * 512 + (kt << 6) + (lk << 4)) ^ ((row & 7) << 4);
        return *(const bf16x8*)(B + off);
    };
    auto ldXs = [&](int mt, int kt) -> bf16x8 {
        int row = (mt << 4) + lr;
        int off = (row * 128 + (kt << 6) + (lk << 4)) ^ ((row & 7) << 4);
        return *(const bf16x8*)(Xs + off);
    };
    auto ldDs = [&](int mt) -> bf16x8 {
        int row = (mt << 4) + lr;
        int off = (row * 64 + (lk << 4)) ^ ((row & 3) << 4);
        return *(const bf16x8*)(Ds + off);
    };

    // GEMM layer. KT = K/32, NT = N-tiles/wave, NTn = next layer's NT (0=none).
    auto gemm = [&](auto KTt, auto NTt, auto NTnt, auto&& getA,
                    const unsigned short* W, int Kp, const float* bias, bool dorelu,
                    char* dst, const unsigned short* Wn, int Kpn, int cbn) {
        constexpr int KT  = decltype(KTt)::value;
        constexpr int NT  = decltype(NTt)::value;
        constexpr int NTn = decltype(NTnt)::value;
        const int colbase = wave * (NT << 4);
        const unsigned short* Wb = W + (size_t)(colbase + lr) * Kp + (lk << 3);
        const unsigned short* Wbn = (NTn > 0) ? Wn + (size_t)(cbn + lr) * Kpn + (lk << 3) : nullptr;

        // bias folded into acc init (neuron = colbase + nt*16 + lk*4 + e)
        f32x4 acc[4][NT];
        {
            f32x4 bfr[NT];
#pragma unroll
            for (int nt = 0; nt < NT; ++nt)
                bfr[nt] = *(const f32x4*)(bias + colbase + (nt << 4) + (lk << 2));
#pragma unroll
            for (int mt = 0; mt < 4; ++mt)
#pragma unroll
                for (int nt = 0; nt < NT; ++nt) acc[mt][nt] = bfr[nt];
        }

        bf16x8 aC[4], aN[4];
#pragma unroll
        for (int mt = 0; mt < 4; ++mt) { aC[mt] = getA(mt, 0); aN[mt] = aC[mt]; }

#pragma unroll
        for (int kt = 0; kt < KT; ++kt) {
            // B prefetch for index kt+2 (wraps into next layer's kt0/kt1)
            if (kt + 2 < KT) {
#pragma unroll
                for (int nt = 0; nt < NT; ++nt)
                    bp2[nt] = *(const bf16x8*)(Wb + (size_t)(nt << 4) * Kp + ((kt + 2) << 5));
            } else if (NTn > 0) {
#pragma unroll
                for (int nt = 0; nt < (NTn > 0 ? NTn : 1); ++nt)
                    bp2[nt] = *(const bf16x8*)(Wbn + (size_t)(nt << 4) * Kpn + ((kt + 2 - KT) << 5));
            }
            // A prefetch distance 1
            if (kt + 1 < KT) {
#pragma unroll
                for (int mt = 0; mt < 4; ++mt) aN[mt] = getA(mt, kt + 1);
            }
            __builtin_amdgcn_s_setprio(1);
#pragma unroll
            for (int nt = 0; nt < NT; ++nt) {
#pragma unroll
                for (int mt = 0; mt < 4; ++mt)
                    acc[mt][nt] = MFMA16(bp0[nt], aC[mt], acc[mt][nt]);  // D=[neuron][batch]
            }
            __builtin_amdgcn_s_setprio(0);
#pragma unroll
            for (int nt = 0; nt < 2; ++nt) { bp0[nt] = bp1[nt]; bp1[nt] = bp2[nt]; }
#pragma unroll
            for (int mt = 0; mt < 4; ++mt) aC[mt] = aN[mt];
        }

        // epilogue: relu, pack 2x bf16 via cvt_pk, one b64 LDS write per tile
#pragma unroll
        for (int nt = 0; nt < NT; ++nt) {
#pragma unroll
            for (int mt = 0; mt < 4; ++mt) {
                f32x4 v = acc[mt][nt];
                if (dorelu) {
#pragma unroll
                    for (int e = 0; e < 4; ++e) v[e] = fmaxf(v[e], 0.f);
                }
                unsigned int lo, hi;
                asm("v_cvt_pk_bf16_f32 %0, %1, %2" : "=v"(lo) : "v"(v[0]), "v"(v[1]));
                asm("v_cvt_pk_bf16_f32 %0, %1, %2" : "=v"(hi) : "v"(v[2]), "v"(v[3]));
                int batch = (mt << 4) + lr;
                int off = (batch * 512 + ((colbase + (nt << 4) + (lk << 2)) << 1)) ^ ((batch & 7) << 4);
                uint32x2 w2 = {lo, hi};
                *(uint32x2*)(dst + off) = w2;
            }
        }
    };

    const unsigned short* Wt = P.Wt;
    char* cur = Hs0;
    char* alt = Hs1;

    // L0: K=64 from Xs -> cur; next = W1
    gemm(ic_t<2>{}, ic_t<2>{}, ic_t<2>{},
         [&](int mt, int kt) { return ldXs(mt, kt); },
         Wt + OFF_W0, 64, P.b[0], true, cur, Wt + OFF_W1, 256, wave << 5);
    __syncthreads();

    // L1-3
    {
        const unsigned short* Wc[3] = {Wt + OFF_W1, Wt + OFF_W2, Wt + OFF_W3};
        const unsigned short* Wn[3] = {Wt + OFF_W2, Wt + OFF_W3, Wt + OFF_W4};
        const int Kpn[3] = {256, 256, 320};
        const float* bc[3] = {P.b[1], P.b[2], P.b[3]};
        for (int i = 0; i < 3; ++i) {
            gemm(ic_t<8>{}, ic_t<2>{}, ic_t<2>{},
                 [&](int mt, int kt) { return ldH(cur, mt, kt); },
                 Wc[i], 256, bc[i], true, alt, Wn[i], Kpn[i], wave << 5);
            __syncthreads();
            char* tmp = cur; cur = alt; alt = tmp;
        }
    }

    // L4: K=320 = [xyz(64) | h(256)]; next = W5
    gemm(ic_t<10>{}, ic_t<2>{}, ic_t<2>{},
         [&](int mt, int kt) { return (kt < 2) ? ldXs(mt, kt) : ldH(cur, mt, kt - 2); },
         Wt + OFF_W4, 320, P.b[4], true, alt, Wt + OFF_W5, 256, wave << 5);
    __syncthreads();
    { char* tmp = cur; cur = alt; alt = tmp; }

    // L5-7
    {
        const unsigned short* Wc[3] = {Wt + OFF_W5, Wt + OFF_W6, Wt + OFF_W7};
        const unsigned short* Wn[3] = {Wt + OFF_W6, Wt + OFF_W7, Wt + OFF_WF};
        const float* bc[3] = {P.b[5], P.b[6], P.b[7]};
        for (int i = 0; i < 3; ++i) {
            gemm(ic_t<8>{}, ic_t<2>{}, ic_t<2>{},
                 [&](int mt, int kt) { return ldH(cur, mt, kt); },
                 Wc[i], 256, bc[i], true, alt, Wn[i], 256, wave << 5);
            __syncthreads();
            char* tmp = cur; cur = alt; alt = tmp;
        }
    }
    // cur = h (layer-7 out)

    // sigma = h @ ws + bs (read-only on cur; 8 threads/row over 256 cols)
    float sig;
    {
        int rr = t >> 3, q = t & 7;
        float sp = 0.f;
#pragma unroll
        for (int j = 0; j < 4; ++j) {
            int cb = (q << 5) + (j << 3);
            bf16x8 h8 = *(const bf16x8*)(cur + ((rr * 512 + (cb << 1)) ^ ((rr & 7) << 4)));
#pragma unroll
            for (int e = 0; e < 8; ++e) sp += (float)h8[e] * P.wsv[cb + e];
        }
        sp += __shfl_xor(sp, 1);
        sp += __shfl_xor(sp, 2);
        sp += __shfl_xor(sp, 4);
        sig = sp + P.bsv[0];
    }

    // xyz_final = h @ wf + bf (no relu); next = WD (NT=1, Kp=288, colbase wave*16)
    gemm(ic_t<8>{}, ic_t<2>{}, ic_t<1>{},
         [&](int mt, int kt) { return ldH(cur, mt, kt); },
         Wt + OFF_WF, 256, P.bfv, false, alt, Wt + OFF_WD, 288, wave << 4);
    __syncthreads();
    { char* tmp = cur; cur = alt; alt = tmp; }
    // cur = xyz_final, alt = h (dead)

    // d = relu([xyz_final | dir] @ wd + bd): KT=9, NT=1 -> alt cols 0..127
    gemm(ic_t<9>{}, ic_t<1>{}, ic_t<0>{},
         [&](int mt, int kt) { return (kt < 8) ? ldH(cur, mt, kt) : ldDs(mt); },
         Wt + OFF_WD, 288, P.bdv, true, alt, nullptr, 0, 0);
    __syncthreads();

    // rgb = sigmoid(d @ wr + br); fused float4 store {r,g,b,sigma}
    {
        int rr = t >> 3, q = t & 7;
        float c0 = 0.f, c1 = 0.f, c2 = 0.f;
#pragma unroll
        for (int j = 0; j < 2; ++j) {
            int kb = (q << 4) + (j << 3);
            bf16x8 d8 = *(const bf16x8*)(alt + ((rr * 512 + (kb << 1)) ^ ((rr & 7) << 4)));
#pragma unroll
            for (int e = 0; e < 8; ++e) {
                float dv = (float)d8[e];
                const float* w = P.wrv + (kb + e) * 3;
                c0 += dv * w[0]; c1 += dv * w[1]; c2 += dv * w[2];
            }
        }
        c0 += __shfl_xor(c0, 1); c0 += __shfl_xor(c0, 2); c0 += __shfl_xor(c0, 4);
        c1 += __shfl_xor(c1, 1); c1 += __shfl_xor(c1, 2); c1 += __shfl_xor(c1, 4);
        c2 += __shfl_xor(c2, 1); c2 += __shfl_xor(c2, 2); c2 += __shfl_xor(c2, 4);
        if (q == 0) {
            float4 o;
            o.x = 1.f / (1.f + __expf(-(c0 + P.brv[0])));
            o.y = 1.f / (1.f + __expf(-(c1 + P.brv[1])));
            o.z = 1.f / (1.f + __expf(-(c2 + P.brv[2])));
            o.w = sig;
            ((float4*)P.out)[blockRow + rr] = o;
        }
    }
}

extern "C" void kernel_launch(void* const* d_in, const int* in_sizes, int n_in,
                              void* d_out, int out_size, void* d_ws, size_t ws_size,
                              hipStream_t stream) {
    const float* x = (const float*)d_in[0];
    const float* w[8];
    const float* b[8];
    for (int i = 0; i < 8; ++i) {
        w[i] = (const float*)d_in[1 + 2 * i];
        b[i] = (const float*)d_in[2 + 2 * i];
    }
    const float* wf  = (const float*)d_in[17];
    const float* bfv = (const float*)d_in[18];
    const float* wd  = (const float*)d_in[19];
    const float* bdv = (const float*)d_in[20];
    const float* wsv = (const float*)d_in[21];
    const float* bsv = (const float*)d_in[22];
    const float* wrv = (const float*)d_in[23];
    const float* brv = (const float*)d_in[24];

    unsigned short* Wt = (unsigned short*)d_ws;

    prep_kernel<<<(W_TOTAL + 255) / 256, 256, 0, stream>>>(
        w[0], w[1], w[2], w[3], w[4], w[5], w[6], w[7], wf, wd, Wt);

    Params P;
    P.x = x; P.Wt = Wt;
    for (int i = 0; i < 8; ++i) P.b[i] = b[i];
    P.bfv = bfv; P.bdv = bdv; P.wsv = wsv; P.bsv = bsv; P.wrv = wrv; P.brv = brv;
    P.out = (float*)d_out;

    nerf_kernel<<<262144 / 64, 512, 0, stream>>>(P);
}

// Round 7
// 614.363 us; speedup vs baseline: 1.1825x; 1.0127x over previous
//
#include <hip/hip_runtime.h>

typedef __bf16  bf16x8 __attribute__((ext_vector_type(8)));
typedef float   f32x4  __attribute__((ext_vector_type(4)));
typedef unsigned int uint32x2 __attribute__((ext_vector_type(2)));

#define MFMA16(a,b,c) __builtin_amdgcn_mfma_f32_16x16x32_bf16((a),(b),(c),0,0,0)

template<int V> struct ic_t { static constexpr int value = V; };

// bf16 weight arena layout in d_ws (elements)
enum : int {
    OFF_W0 = 0,                      // [256][64]
    OFF_W1 = OFF_W0 + 256 * 64,      // [256][256]
    OFF_W2 = OFF_W1 + 256 * 256,
    OFF_W3 = OFF_W2 + 256 * 256,
    OFF_W4 = OFF_W3 + 256 * 256,     // [256][320]
    OFF_W5 = OFF_W4 + 256 * 320,
    OFF_W6 = OFF_W5 + 256 * 256,
    OFF_W7 = OFF_W6 + 256 * 256,
    OFF_WF = OFF_W7 + 256 * 256,     // [256][256]
    OFF_WD = OFF_WF + 256 * 256,     // [128][288]
    W_TOTAL = OFF_WD + 128 * 288
};

__device__ __forceinline__ unsigned short f2bf(float f) {
    unsigned int u = __float_as_uint(f);
    u += 0x7FFFu + ((u >> 16) & 1u);
    return (unsigned short)(u >> 16);
}

// Soft barrier: make LDS writes visible, rendezvous, but DO NOT drain vmcnt —
// global weight prefetches stay in flight across the barrier (T4 pattern).
__device__ __forceinline__ void soft_barrier() {
    asm volatile("s_waitcnt lgkmcnt(0)" ::: "memory");
    __builtin_amdgcn_s_barrier();
}

__device__ __forceinline__ void prep_one(const float* __restrict__ src,
                                         unsigned short* __restrict__ dst,
                                         int fout, int Kp, int n1, int n2, int n3,
                                         int idx) {
    int n = idx / Kp;
    int k = idx - n * Kp;
    float v = 0.f;
    if (k < n1)                 v = src[k * fout + n];
    else if (k >= n2 && k < n3) v = src[(k - (n2 - n1)) * fout + n];
    dst[n * Kp + k] = f2bf(v);
}

__global__ void prep_kernel(const float* w0, const float* w1, const float* w2,
                            const float* w3, const float* w4, const float* w5,
                            const float* w6, const float* w7, const float* wf,
                            const float* wd, unsigned short* dst) {
    int i = blockIdx.x * 256 + threadIdx.x;
    if (i < 256 * 64)  { prep_one(w0, dst + OFF_W0, 256,  64,  63,  64,  64, i); return; }
    i -= 256 * 64;
    if (i < 256 * 256) { prep_one(w1, dst + OFF_W1, 256, 256, 256, 256, 256, i); return; }
    i -= 256 * 256;
    if (i < 256 * 256) { prep_one(w2, dst + OFF_W2, 256, 256, 256, 256, 256, i); return; }
    i -= 256 * 256;
    if (i < 256 * 256) { prep_one(w3, dst + OFF_W3, 256, 256, 256, 256, 256, i); return; }
    i -= 256 * 256;
    if (i < 256 * 320) { prep_one(w4, dst + OFF_W4, 256, 320,  63,  64, 320, i); return; }
    i -= 256 * 320;
    if (i < 256 * 256) { prep_one(w5, dst + OFF_W5, 256, 256, 256, 256, 256, i); return; }
    i -= 256 * 256;
    if (i < 256 * 256) { prep_one(w6, dst + OFF_W6, 256, 256, 256, 256, 256, i); return; }
    i -= 256 * 256;
    if (i < 256 * 256) { prep_one(w7, dst + OFF_W7, 256, 256, 256, 256, 256, i); return; }
    i -= 256 * 256;
    if (i < 256 * 256) { prep_one(wf, dst + OFF_WF, 256, 256, 256, 256, 256, i); return; }
    i -= 256 * 256;
    if (i < 128 * 288) { prep_one(wd, dst + OFF_WD, 128, 288, 286, 288, 288, i); return; }
}

struct Params {
    const float* x;
    const unsigned short* Wt;
    const float* b[8];
    const float* bfv;
    const float* bdv;
    const float* wsv;
    const float* bsv;
    const float* wrv;
    const float* brv;
    float* out;
};

// 64 rows/block, 8 waves (512 thr), N-split 32 cols/wave. Swapped-operand MFMA
// (D=[neuron][batch]) -> packed b64 epilogue, bias folded into acc init.
// Depth-3 B prefetch; layer tail batch-issues next layer's kt0-2; soft
// barriers keep those loads in flight across the layer boundary.
__global__ __launch_bounds__(512, 2) void nerf_kernel(Params P) {
    __shared__ char Hs0[32768];   // [64][256] bf16, swz ^((row&7)<<4)
    __shared__ char Hs1[32768];
    __shared__ char Xs[8192];     // [64][64] bf16, swz ^((row&7)<<4)
    __shared__ char Ds[4096];     // [64][32] bf16, swz ^((row&3)<<4) (in-row)

    const int t    = threadIdx.x;
    const int lane = t & 63;
    const int wave = t >> 6;          // 0..7
    const int lr   = lane & 15;
    const int lk   = lane >> 4;
    const int blockRow = blockIdx.x << 6;

    // ---- B pipeline (persistent across layers): bp0/bp1/bp2 = kt0/1/2 frags
    bf16x8 bp0[2], bp1[2], bp2[2];
    {   // preload layer-0 kt0/kt1 (overlaps staging below); L0 has only 2 kts
        const unsigned short* Wb0 = P.Wt + OFF_W0 + (size_t)((wave << 5) + lr) * 64 + (lk << 3);
#pragma unroll
        for (int nt = 0; nt < 2; ++nt) {
            bp0[nt] = *(const bf16x8*)(Wb0 + (size_t)(nt << 4) * 64);
            bp1[nt] = *(const bf16x8*)(Wb0 + (size_t)(nt << 4) * 64 + 32);
            bp2[nt] = bp1[nt];
        }
    }

    // ---- stage x coalesced into Xs/Ds ----
    {
        const float4* xb = (const float4*)(P.x + (size_t)blockRow * 93);
        for (int i = t; i < 1488; i += 512) {          // 64*93/4
            float4 v = xb[i];
            float vv[4] = {v.x, v.y, v.z, v.w};
#pragma unroll
            for (int j = 0; j < 4; ++j) {
                int e = (i << 2) + j;
                int r = e / 93;
                int c = e - r * 93;
                __bf16 us = (__bf16)vv[j];
                if (c < 63)
                    *(__bf16*)(Xs + ((r * 128 + c * 2) ^ ((r & 7) << 4))) = us;
                else
                    *(__bf16*)(Ds + ((r * 64 + (c - 63) * 2) ^ ((r & 3) << 4))) = us;
            }
        }
        if (t < 64) {  // zero pads: Xs col63, Ds cols 30,31
            int r = t;
            *(__bf16*)(Xs + ((r * 128 + 126) ^ ((r & 7) << 4))) = (__bf16)0.f;
            *(__bf16*)(Ds + ((r * 64 + 60) ^ ((r & 3) << 4))) = (__bf16)0.f;
            *(__bf16*)(Ds + ((r * 64 + 62) ^ ((r & 3) << 4))) = (__bf16)0.f;
        }
    }
    soft_barrier();

    // A-fragment getters (activation rows): row = mt*16+lr, k contiguous 16B
    auto ldH = [&](const char* B, int mt, int kt) -> bf16x8 {
        int row = (mt << 4) + lr;
        int off = (row * 512 + (kt << 6) + (lk << 4)) ^ ((row & 7) << 4);
        return *(const bf16x8*)(B + off);
    };
    auto ldXs = [&](int mt, int kt) -> bf16x8 {
        int row = (mt << 4) + lr;
        int off = (row * 128 + (kt << 6) + (lk << 4)) ^ ((row & 7) << 4);
        return *(const bf16x8*)(Xs + off);
    };
    auto ldDs = [&](int mt) -> bf16x8 {
        int row = (mt << 4) + lr;
        int off = (row * 64 + (lk << 4)) ^ ((row & 3) << 4);
        return *(const bf16x8*)(Ds + off);
    };

    // GEMM layer. KT = K/32, NT = N-tiles/wave, NTn = next layer's NT (0=none).
    // Entry convention: bp0..bp2 hold this layer's kt0..kt2 B-fragments.
    // Exit: bp0..bp2 hold NEXT layer's kt0..kt2 (loads issued before epilogue,
    // in flight across the soft barrier).
    auto gemm = [&](auto KTt, auto NTt, auto NTnt, auto&& getA,
                    const unsigned short* W, int Kp, const float* bias, bool dorelu,
                    char* dst, const unsigned short* Wn, int Kpn, int cbn) {
        constexpr int KT  = decltype(KTt)::value;
        constexpr int NT  = decltype(NTt)::value;
        constexpr int NTn = decltype(NTnt)::value;
        const int colbase = wave * (NT << 4);
        const unsigned short* Wb = W + (size_t)(colbase + lr) * Kp + (lk << 3);

        // bias folded into acc init (neuron = colbase + nt*16 + lk*4 + e)
        f32x4 acc[4][NT];
        {
            f32x4 bfr[NT];
#pragma unroll
            for (int nt = 0; nt < NT; ++nt)
                bfr[nt] = *(const f32x4*)(bias + colbase + (nt << 4) + (lk << 2));
#pragma unroll
            for (int mt = 0; mt < 4; ++mt)
#pragma unroll
                for (int nt = 0; nt < NT; ++nt) acc[mt][nt] = bfr[nt];
        }

        bf16x8 aC[4], aN[4];
#pragma unroll
        for (int mt = 0; mt < 4; ++mt) { aC[mt] = getA(mt, 0); aN[mt] = aC[mt]; }

#pragma unroll
        for (int kt = 0; kt < KT; ++kt) {
            // depth-3 B prefetch for kt+3 (within this layer)
            bf16x8 bpN[2];
#pragma unroll
            for (int nt = 0; nt < NT; ++nt) {
                if (kt + 3 < KT)
                    bpN[nt] = *(const bf16x8*)(Wb + (size_t)(nt << 4) * Kp + ((kt + 3) << 5));
                else
                    bpN[nt] = bp2[nt];
            }
            // A prefetch distance 1
            if (kt + 1 < KT) {
#pragma unroll
                for (int mt = 0; mt < 4; ++mt) aN[mt] = getA(mt, kt + 1);
            }
            __builtin_amdgcn_s_setprio(1);
#pragma unroll
            for (int nt = 0; nt < NT; ++nt) {
#pragma unroll
                for (int mt = 0; mt < 4; ++mt)
                    acc[mt][nt] = MFMA16(bp0[nt], aC[mt], acc[mt][nt]);  // D=[neuron][batch]
            }
            __builtin_amdgcn_s_setprio(0);
#pragma unroll
            for (int nt = 0; nt < 2; ++nt) { bp0[nt] = bp1[nt]; bp1[nt] = bp2[nt]; bp2[nt] = bpN[nt]; }
#pragma unroll
            for (int mt = 0; mt < 4; ++mt) aC[mt] = aN[mt];
        }

        // batch-issue NEXT layer's kt0..2 — they fly across the barrier
        if (NTn > 0) {
            const unsigned short* Wbn = Wn + (size_t)(cbn + lr) * Kpn + (lk << 3);
#pragma unroll
            for (int nt = 0; nt < (NTn > 0 ? NTn : 1); ++nt) {
                bp0[nt] = *(const bf16x8*)(Wbn + (size_t)(nt << 4) * Kpn);
                bp1[nt] = *(const bf16x8*)(Wbn + (size_t)(nt << 4) * Kpn + 32);
                bp2[nt] = *(const bf16x8*)(Wbn + (size_t)(nt << 4) * Kpn + 64);
            }
        }

        // epilogue: relu, pack 2x bf16 via cvt_pk, one b64 LDS write per tile
#pragma unroll
        for (int nt = 0; nt < NT; ++nt) {
#pragma unroll
            for (int mt = 0; mt < 4; ++mt) {
                f32x4 v = acc[mt][nt];
                if (dorelu) {
#pragma unroll
                    for (int e = 0; e < 4; ++e) v[e] = fmaxf(v[e], 0.f);
                }
                unsigned int lo, hi;
                asm("v_cvt_pk_bf16_f32 %0, %1, %2" : "=v"(lo) : "v"(v[0]), "v"(v[1]));
                asm("v_cvt_pk_bf16_f32 %0, %1, %2" : "=v"(hi) : "v"(v[2]), "v"(v[3]));
                int batch = (mt << 4) + lr;
                int off = (batch * 512 + ((colbase + (nt << 4) + (lk << 2)) << 1)) ^ ((batch & 7) << 4);
                uint32x2 w2 = {lo, hi};
                *(uint32x2*)(dst + off) = w2;
            }
        }
    };

    const unsigned short* Wt = P.Wt;
    char* cur = Hs0;
    char* alt = Hs1;

    // L0: K=64 from Xs -> cur; next = W1
    gemm(ic_t<2>{}, ic_t<2>{}, ic_t<2>{},
         [&](int mt, int kt) { return ldXs(mt, kt); },
         Wt + OFF_W0, 64, P.b[0], true, cur, Wt + OFF_W1, 256, wave << 5);
    soft_barrier();

    // L1-3
    {
        const unsigned short* Wc[3] = {Wt + OFF_W1, Wt + OFF_W2, Wt + OFF_W3};
        const unsigned short* Wn[3] = {Wt + OFF_W2, Wt + OFF_W3, Wt + OFF_W4};
        const int Kpn[3] = {256, 256, 320};
        const float* bc[3] = {P.b[1], P.b[2], P.b[3]};
        for (int i = 0; i < 3; ++i) {
            gemm(ic_t<8>{}, ic_t<2>{}, ic_t<2>{},
                 [&](int mt, int kt) { return ldH(cur, mt, kt); },
                 Wc[i], 256, bc[i], true, alt, Wn[i], Kpn[i], wave << 5);
            soft_barrier();
            char* tmp = cur; cur = alt; alt = tmp;
        }
    }

    // L4: K=320 = [xyz(64) | h(256)]; next = W5
    gemm(ic_t<10>{}, ic_t<2>{}, ic_t<2>{},
         [&](int mt, int kt) { return (kt < 2) ? ldXs(mt, kt) : ldH(cur, mt, kt - 2); },
         Wt + OFF_W4, 320, P.b[4], true, alt, Wt + OFF_W5, 256, wave << 5);
    soft_barrier();
    { char* tmp = cur; cur = alt; alt = tmp; }

    // L5-7
    {
        const unsigned short* Wc[3] = {Wt + OFF_W5, Wt + OFF_W6, Wt + OFF_W7};
        const unsigned short* Wn[3] = {Wt + OFF_W6, Wt + OFF_W7, Wt + OFF_WF};
        const float* bc[3] = {P.b[5], P.b[6], P.b[7]};
        for (int i = 0; i < 3; ++i) {
            gemm(ic_t<8>{}, ic_t<2>{}, ic_t<2>{},
                 [&](int mt, int kt) { return ldH(cur, mt, kt); },
                 Wc[i], 256, bc[i], true, alt, Wn[i], 256, wave << 5);
            soft_barrier();
            char* tmp = cur; cur = alt; alt = tmp;
        }
    }
    // cur = h (layer-7 out)

    // sigma = h @ ws + bs (read-only on cur; 8 threads/row over 256 cols)
    // Placed here so WF's prefetched B-frags gain extra flight time.
    float sig;
    {
        int rr = t >> 3, q = t & 7;
        float sp = 0.f;
#pragma unroll
        for (int j = 0; j < 4; ++j) {
            int cb = (q << 5) + (j << 3);
            bf16x8 h8 = *(const bf16x8*)(cur + ((rr * 512 + (cb << 1)) ^ ((rr & 7) << 4)));
#pragma unroll
            for (int e = 0; e < 8; ++e) sp += (float)h8[e] * P.wsv[cb + e];
        }
        sp += __shfl_xor(sp, 1);
        sp += __shfl_xor(sp, 2);
        sp += __shfl_xor(sp, 4);
        sig = sp + P.bsv[0];
    }

    // xyz_final = h @ wf + bf (no relu); next = WD (NT=1, Kp=288, colbase wave*16)
    gemm(ic_t<8>{}, ic_t<2>{}, ic_t<1>{},
         [&](int mt, int kt) { return ldH(cur, mt, kt); },
         Wt + OFF_WF, 256, P.bfv, false, alt, Wt + OFF_WD, 288, wave << 4);
    soft_barrier();
    { char* tmp = cur; cur = alt; alt = tmp; }
    // cur = xyz_final, alt = h (dead)

    // d = relu([xyz_final | dir] @ wd + bd): KT=9, NT=1 -> alt cols 0..127
    gemm(ic_t<9>{}, ic_t<1>{}, ic_t<0>{},
         [&](int mt, int kt) { return (kt < 8) ? ldH(cur, mt, kt) : ldDs(mt); },
         Wt + OFF_WD, 288, P.bdv, true, alt, nullptr, 0, 0);
    soft_barrier();

    // rgb = sigmoid(d @ wr + br); fused float4 store {r,g,b,sigma}
    {
        int rr = t >> 3, q = t & 7;
        float c0 = 0.f, c1 = 0.f, c2 = 0.f;
#pragma unroll
        for (int j = 0; j < 2; ++j) {
            int kb = (q << 4) + (j << 3);
            bf16x8 d8 = *(const bf16x8*)(alt + ((rr * 512 + (kb << 1)) ^ ((rr & 7) << 4)));
#pragma unroll
            for (int e = 0; e < 8; ++e) {
                float dv = (float)d8[e];
                const float* w = P.wrv + (kb + e) * 3;
                c0 += dv * w[0]; c1 += dv * w[1]; c2 += dv * w[2];
            }
        }
        c0 += __shfl_xor(c0, 1); c0 += __shfl_xor(c0, 2); c0 += __shfl_xor(c0, 4);
        c1 += __shfl_xor(c1, 1); c1 += __shfl_xor(c1, 2); c1 += __shfl_xor(c1, 4);
        c2 += __shfl_xor(c2, 1); c2 += __shfl_xor(c2, 2); c2 += __shfl_xor(c2, 4);
        if (q == 0) {
            float4 o;
            o.x = 1.f / (1.f + __expf(-(c0 + P.brv[0])));
            o.y = 1.f / (1.f + __expf(-(c1 + P.brv[1])));
            o.z = 1.f / (1.f + __expf(-(c2 + P.brv[2])));
            o.w = sig;
            ((float4*)P.out)[blockRow + rr] = o;
        }
    }
}

extern "C" void kernel_launch(void* const* d_in, const int* in_sizes, int n_in,
                              void* d_out, int out_size, void* d_ws, size_t ws_size,
                              hipStream_t stream) {
    const float* x = (const float*)d_in[0];
    const float* w[8];
    const float* b[8];
    for (int i = 0; i < 8; ++i) {
        w[i] = (const float*)d_in[1 + 2 * i];
        b[i] = (const float*)d_in[2 + 2 * i];
    }
    const float* wf  = (const float*)d_in[17];
    const float* bfv = (const float*)d_in[18];
    const float* wd  = (const float*)d_in[19];
    const float* bdv = (const float*)d_in[20];
    const float* wsv = (const float*)d_in[21];
    const float* bsv = (const float*)d_in[22];
    const float* wrv = (const float*)d_in[23];
    const float* brv = (const float*)d_in[24];

    unsigned short* Wt = (unsigned short*)d_ws;

    prep_kernel<<<(W_TOTAL + 255) / 256, 256, 0, stream>>>(
        w[0], w[1], w[2], w[3], w[4], w[5], w[6], w[7], wf, wd, Wt);

    Params P;
    P.x = x; P.Wt = Wt;
    for (int i = 0; i < 8; ++i) P.b[i] = b[i];
    P.bfv = bfv; P.bdv = bdv; P.wsv = wsv; P.bsv = bsv; P.wrv = wrv; P.brv = brv;
    P.out = (float*)d_out;

    nerf_kernel<<<262144 / 64, 512, 0, stream>>>(P);
}